// Round 1
// baseline (18472.113 us; speedup 1.0000x reference)
//
#include <hip/hip_runtime.h>

typedef __attribute__((ext_vector_type(8))) short short8;
typedef __attribute__((ext_vector_type(4))) float floatx4;

#define TT 512
#define BB 64
#define II 256
#define HH 2048
#define BH (BB * HH)

#define MFMA(a, b, c) __builtin_amdgcn_mfma_f32_16x16x32_bf16(a, b, c, 0, 0, 0)

__device__ __forceinline__ short f2bf(float f) {
  unsigned u = __builtin_bit_cast(unsigned, f);
  u = (u + 0x7fffu + ((u >> 16) & 1u)) >> 16;
  return (short)u;
}
__device__ __forceinline__ float bf2f(short s) {
  unsigned u = ((unsigned)(unsigned short)s) << 16;
  return __builtin_bit_cast(float, u);
}

// ---- pack W_hat [2048][2048] fp32 -> MFMA-B-fragment-ordered bf16 hi/lo ----
// PW[(ntile*64 + kblock)*64 + lane] = short8 of W[ntile*16 + (lane&15)][kblock*32 + (lane>>4)*8 + j]
__global__ __launch_bounds__(64) void pack_what(const float* __restrict__ What,
                                                short8* __restrict__ PWhi,
                                                short8* __restrict__ PWlo) {
  const int ntile = blockIdx.x >> 6;
  const int kb = blockIdx.x & 63;
  const int L = threadIdx.x;
  const int lm = L & 15, lq = L >> 4;
  const float* p = What + (size_t)(ntile * 16 + lm) * HH + kb * 32 + lq * 8;
  short8 hi, lo;
#pragma unroll
  for (int j = 0; j < 8; ++j) {
    float f = p[j];
    short h = f2bf(f);
    hi[j] = h;
    lo[j] = f2bf(f - bf2f(h));
  }
  const size_t o = (size_t)blockIdx.x * 64 + L;
  PWhi[o] = hi;
  PWlo[o] = lo;
}

// ---- initial state -> bf16 hi/lo slot0; zero barrier flags ----
__global__ __launch_bounds__(256) void prep_state(const float* __restrict__ s0,
                                                  short* __restrict__ Shi,
                                                  short* __restrict__ Slo,
                                                  unsigned* __restrict__ flags) {
  int i = blockIdx.x * 256 + threadIdx.x;  // 131072 total
  if (i < 4096) flags[i] = 0;              // 256 flags * 16-word pad
  float f = s0[i];
  short h = f2bf(f);
  Shi[i] = h;
  Slo[i] = f2bf(f - bf2f(h));
}

// ---- u = X @ Win^T into d_out (verified round-2 kernel, unchanged) ----
__global__ __launch_bounds__(256) void ugemm(const float* __restrict__ X,
                                             const float* __restrict__ Win,
                                             float* __restrict__ U) {
  const int w = threadIdx.x >> 6;
  const int L = threadIdx.x & 63;
  const int lm = L & 15, lq = L >> 4;
  const int m0 = blockIdx.x * 128 + (w >> 1) * 64;
  const int n0 = blockIdx.y * 64 + (w & 1) * 32;

  short8 Bhi[2][8], Blo[2][8];
#pragma unroll
  for (int nt = 0; nt < 2; ++nt)
#pragma unroll
    for (int kt = 0; kt < 8; ++kt) {
      const float* p = Win + (n0 + nt * 16 + lm) * II + kt * 32 + lq * 8;
      short8 hi, lo;
#pragma unroll
      for (int j = 0; j < 8; ++j) {
        float f = p[j];
        short h = f2bf(f);
        hi[j] = h;
        lo[j] = f2bf(f - bf2f(h));
      }
      Bhi[nt][kt] = hi;
      Blo[nt][kt] = lo;
    }

#pragma unroll 1
  for (int mt = 0; mt < 4; ++mt) {
    short8 Ahi[8], Alo[8];
    const int r = m0 + mt * 16 + lm;
#pragma unroll
    for (int kt = 0; kt < 8; ++kt) {
      const float* p = X + (size_t)r * II + kt * 32 + lq * 8;
      short8 hi, lo;
#pragma unroll
      for (int j = 0; j < 8; ++j) {
        float f = p[j];
        short h = f2bf(f);
        hi[j] = h;
        lo[j] = f2bf(f - bf2f(h));
      }
      Ahi[kt] = hi;
      Alo[kt] = lo;
    }
#pragma unroll
    for (int nt = 0; nt < 2; ++nt) {
      floatx4 acc = {0.f, 0.f, 0.f, 0.f};
#pragma unroll
      for (int kt = 0; kt < 8; ++kt) {
        acc = MFMA(Ahi[kt], Bhi[nt][kt], acc);
        acc = MFMA(Ahi[kt], Blo[nt][kt], acc);
        acc = MFMA(Alo[kt], Bhi[nt][kt], acc);
      }
#pragma unroll
      for (int rr = 0; rr < 4; ++rr) {
        int row = m0 + mt * 16 + lq * 4 + rr;
        int col = n0 + nt * 16 + lm;
        U[(size_t)row * HH + col] = acc[rr];
      }
    }
  }
}

// ---- persistent recurrence: all 512 steps in one cooperative launch ----
// 256 blocks x 256 thr, 1 block/CU. block = (mhalf: 32 rows, ntile: 16 cols),
// 4 waves k-split (512 each). Each wave holds its W slice in 128 VGPRs for the
// whole kernel (W never re-fetched). Triple-buffered state -> 1 grid barrier
// per step (flag-array barrier: no same-address atomic contention).
__global__ __launch_bounds__(256, 1) void recurrence(
    const short8* __restrict__ PWhi, const short8* __restrict__ PWlo,
    short* __restrict__ SH, short* __restrict__ SL,
    float* __restrict__ out, unsigned* __restrict__ flags) {
  __shared__ float red[4][32][17];
  const int tid = threadIdx.x;
  const int w = tid >> 6;
  const int L = tid & 63;
  const int lm = L & 15, lq = L >> 4;
  const int mhalf = blockIdx.x & 1;
  const int ntile = blockIdx.x >> 1;  // 0..127
  const int mbase = mhalf * 32;
  const int kw = w * 512;

  // W fragments -> registers, once. 16 kt x (hi,lo) x 4 VGPR = 128 VGPR.
  short8 Wh[16], Wl[16];
  const size_t wb = ((size_t)ntile * 64 + (kw >> 5)) * 64 + L;
#pragma unroll
  for (int kt = 0; kt < 16; ++kt) {
    Wh[kt] = PWhi[wb + (size_t)kt * 64];
    Wl[kt] = PWlo[wb + (size_t)kt * 64];
  }

  const int r0 = (mbase + lm) * HH;
  const int r1 = (mbase + 16 + lm) * HH;
  // epilogue: 2 outputs/thread
  const int ecol = tid & 15;
  const int e0row = tid >> 4;        // 0..15
  const int e1row = 16 + e0row;      // 16..31
  const int idx0 = (mbase + e0row) * HH + ntile * 16 + ecol;
  const int idx1 = (mbase + e1row) * HH + ntile * 16 + ecol;

  int slot = 0;
  for (int t = 0; t < TT; ++t) {
    int nslot = slot + 1;
    if (nslot == 3) nslot = 0;
    const short* curH = SH + slot * BH;
    const short* curL = SL + slot * BH;
    short* nxtH = SH + nslot * BH;
    short* nxtL = SL + nslot * BH;
    float* ot = out + (size_t)t * BH;

    // prefetch epilogue operands early (HBM u under the k-loop)
    float u0 = ot[idx0], u1 = ot[idx1];
    float sp0 = bf2f(curH[idx0]) + bf2f(curL[idx0]);
    float sp1 = bf2f(curH[idx1]) + bf2f(curL[idx1]);

    // 6 accumulators: break the MFMA dependency chains (distance 6)
    floatx4 a00 = {0.f, 0.f, 0.f, 0.f}, a01 = a00, a02 = a00;
    floatx4 a10 = a00, a11 = a00, a12 = a00;
#pragma unroll
    for (int kt = 0; kt < 16; ++kt) {
      const int k0 = kw + kt * 32 + lq * 8;
      short8 x0h = *(const short8*)(curH + r0 + k0);
      short8 x0l = *(const short8*)(curL + r0 + k0);
      short8 x1h = *(const short8*)(curH + r1 + k0);
      short8 x1l = *(const short8*)(curL + r1 + k0);
      a00 = MFMA(x0h, Wh[kt], a00);
      a10 = MFMA(x1h, Wh[kt], a10);
      a01 = MFMA(x0h, Wl[kt], a01);
      a11 = MFMA(x1h, Wl[kt], a11);
      a02 = MFMA(x0l, Wh[kt], a02);
      a12 = MFMA(x1l, Wh[kt], a12);
    }
    floatx4 s0v = a00 + a01 + a02;
    floatx4 s1v = a10 + a11 + a12;

    // C layout: col = lane&15, row = (lane>>4)*4 + reg
#pragma unroll
    for (int r = 0; r < 4; ++r) {
      red[w][lq * 4 + r][lm] = s0v[r];
      red[w][16 + lq * 4 + r][lm] = s1v[r];
    }
    __syncthreads();

    float z0 = u0, z1 = u1;
#pragma unroll
    for (int ww = 0; ww < 4; ++ww) {
      z0 += red[ww][e0row][ecol];
      z1 += red[ww][e1row][ecol];
    }
    const float sn0 = 0.5f * (sp0 + tanhf(z0));
    const float sn1 = 0.5f * (sp1 + tanhf(z1));
    ot[idx0] = sn0;
    ot[idx1] = sn1;
    const short h0 = f2bf(sn0), h1 = f2bf(sn1);
    nxtH[idx0] = h0;
    nxtL[idx0] = f2bf(sn0 - bf2f(h0));
    nxtH[idx1] = h1;
    nxtL[idx1] = f2bf(sn1 - bf2f(h1));

    // ---- grid barrier (one per step; triple-buffer makes this sufficient) ----
    __syncthreads();  // drains this block's stores (vmcnt(0) before s_barrier)
    const unsigned g = (unsigned)(t + 1);
    if (tid == 0)
      __hip_atomic_store(&flags[(unsigned)blockIdx.x * 16u], g,
                         __ATOMIC_RELEASE, __HIP_MEMORY_SCOPE_AGENT);
    // 256 threads each watch one block's flag: no atomic-RMW serialization
    while (__hip_atomic_load(&flags[(unsigned)tid * 16u],
                             __ATOMIC_ACQUIRE, __HIP_MEMORY_SCOPE_AGENT) < g)
      __builtin_amdgcn_s_sleep(1);
    __syncthreads();

    slot = nslot;
  }
}

extern "C" void kernel_launch(void* const* d_in, const int* in_sizes, int n_in,
                              void* d_out, int out_size, void* d_ws, size_t ws_size,
                              hipStream_t stream) {
  const float* x = (const float*)d_in[0];     // [512,64,256]
  const float* s0 = (const float*)d_in[1];    // [64,2048]
  const float* Win = (const float*)d_in[2];   // [2048,256]
  const float* What = (const float*)d_in[3];  // [2048,2048]
  float* out = (float*)d_out;                 // [512,64,2048]

  short8* PWhi = (short8*)d_ws;                       // 8 MB
  short8* PWlo = PWhi + (size_t)HH * HH / 8;          // 8 MB
  short* SH = (short*)(PWlo + (size_t)HH * HH / 8);   // 3 slots x 256 KB
  short* SL = SH + 3 * BH;                            // 3 slots x 256 KB
  unsigned* flags = (unsigned*)(SL + 3 * BH);         // 16 KB

  pack_what<<<8192, 64, 0, stream>>>(What, PWhi, PWlo);
  prep_state<<<512, 256, 0, stream>>>(s0, SH, SL, flags);
  ugemm<<<dim3(256, 32), 256, 0, stream>>>(x, Win, out);

  void* kargs[] = {&PWhi, &PWlo, &SH, &SL, &out, &flags};
  hipError_t ce = hipLaunchCooperativeKernel(
      reinterpret_cast<void*>(&recurrence), dim3(256), dim3(256), kargs, 0, stream);
  if (ce != hipSuccess) {
    // fallback: plain launch of the same persistent kernel (256 blocks on 256
    // CUs, 1 block/CU occupancy -> co-resident in practice)
    recurrence<<<256, 256, 0, stream>>>(PWhi, PWlo, SH, SL, out, flags);
  }
}